// Round 4
// baseline (791.145 us; speedup 1.0000x reference)
//
#include <hip/hip_runtime.h>
#include <cstdint>

typedef unsigned short ushort_t;
typedef __attribute__((ext_vector_type(8))) short bf16x8;
typedef __attribute__((ext_vector_type(4))) float f32x4;

#define S_LEN 1024
#define DHEAD 64

__device__ inline ushort_t f2bf(float f) {
    union { float f; uint32_t u; } c; c.f = f;
    uint32_t u = c.u;
    uint32_t r = u + 0x7FFFu + ((u >> 16) & 1u);
    return (ushort_t)(r >> 16);
}
__device__ inline float bf2f(ushort_t h) {
    union { uint32_t u; float f; } c; c.u = ((uint32_t)h) << 16;
    return c.f;
}
__device__ inline bf16x8 load8(const ushort_t* p) {
    union { uint4 u; bf16x8 v; } c;
    c.u = *reinterpret_cast<const uint4*>(p);
    return c.v;
}

// ---------------------------------------------------------------------------
// prep_w: tiled transpose+convert 5 weights (512x512) fp32 -> bf16 W^T
// ---------------------------------------------------------------------------
__global__ __launch_bounds__(256) void prep_w(
    const float* __restrict__ wq, const float* __restrict__ wk,
    const float* __restrict__ wv, const float* __restrict__ wp,
    const float* __restrict__ wo, ushort_t* __restrict__ ws) {
    __shared__ float tile[64][65];
    int wi = blockIdx.z;
    const float* src = wi == 0 ? wq : wi == 1 ? wk : wi == 2 ? wv : wi == 3 ? wp : wo;
    int cx = blockIdx.x * 64, ry = blockIdx.y * 64;
    int t = threadIdx.x;
    int tr = t >> 4, tc = (t & 15) * 4;
#pragma unroll
    for (int i = 0; i < 4; i++) {
        int r = tr + i * 16;
        float4 f = *reinterpret_cast<const float4*>(src + (size_t)(ry + r) * 512 + cx + tc);
        tile[r][tc] = f.x; tile[r][tc + 1] = f.y; tile[r][tc + 2] = f.z; tile[r][tc + 3] = f.w;
    }
    __syncthreads();
    ushort_t* dst = ws + (size_t)wi * 262144;
#pragma unroll
    for (int i = 0; i < 4; i++) {
        int r = tr + i * 16;
        ushort4 o;
        o.x = f2bf(tile[tc][r]); o.y = f2bf(tile[tc + 1][r]);
        o.z = f2bf(tile[tc + 2][r]); o.w = f2bf(tile[tc + 3][r]);
        *reinterpret_cast<ushort4*>(dst + (size_t)(cx + r) * 512 + ry + tc) = o;
    }
}

// ---------------------------------------------------------------------------
// prep_act: elementwise fp32 -> bf16 for the 4 activations (8192x512 each)
// ---------------------------------------------------------------------------
__global__ __launch_bounds__(256) void prep_act(
    const float* __restrict__ q, const float* __restrict__ k,
    const float* __restrict__ v, const float* __restrict__ p,
    ushort_t* __restrict__ actb) {
    int t = blockIdx.x * 256 + threadIdx.x;   // 0..1048575
    int sec = blockIdx.y;
    const float* src = sec == 0 ? q : sec == 1 ? k : sec == 2 ? v : p;
    ushort_t* dst = actb + (size_t)sec * 4194304;
    float4 f = reinterpret_cast<const float4*>(src)[t];
    ushort4 o;
    o.x = f2bf(f.x); o.y = f2bf(f.y); o.z = f2bf(f.z); o.w = f2bf(f.w);
    *reinterpret_cast<ushort4*>(dst + (size_t)t * 4) = o;
}

// ---------------------------------------------------------------------------
// merged projection GEMM: z=0 Q (->Qu,Qv), z=1 K (->Kp), z=2 P (->Pp),
// z=3 V (->Vt transposed [bh][dh][s]). CVT=1: A fp32, convert during staging.
// CVT=0: A bf16 from pre-converted act buffer (pure b128 staging).
// ---------------------------------------------------------------------------
template<int CVT>
__global__ __launch_bounds__(256) void proj_gemm(
    const float* __restrict__ qa, const float* __restrict__ ka,
    const float* __restrict__ va, const float* __restrict__ pa,
    const ushort_t* __restrict__ actb,
    const ushort_t* __restrict__ wT,
    const float* __restrict__ bq, const float* __restrict__ bk,
    const float* __restrict__ bv,
    const float* __restrict__ ub, const float* __restrict__ vb,
    ushort_t* __restrict__ Qu, ushort_t* __restrict__ Qv,
    ushort_t* __restrict__ Kp, ushort_t* __restrict__ Pp,
    ushort_t* __restrict__ Vt) {
    __shared__ ushort_t smem[2][128][72];
    int z = blockIdx.z;
    const float* Af = z == 0 ? qa : z == 1 ? ka : z == 2 ? pa : va;
    // act order: 0=q,1=k,2=v,3=p ; z order: 0=q,1=k,2=p,3=v
    const ushort_t* Ab = actb + (size_t)(z == 0 ? 0 : z == 1 ? 1 : z == 2 ? 3 : 2) * 4194304;
    const ushort_t* Bt = wT + (z == 0 ? 0 : z == 1 ? 262144 : z == 2 ? 786432 : 524288);
    const float* bias = z == 0 ? bq : z == 1 ? bk : z == 3 ? bv : nullptr;

    int tid = threadIdx.x;
    int wid = tid >> 6, lane = tid & 63, quad = lane >> 4, l16 = lane & 15;
    int wr = wid >> 1, wc = wid & 1;
    int row0 = blockIdx.y * 128, col0 = blockIdx.x * 128;

    f32x4 acc[4][4];
#pragma unroll
    for (int i = 0; i < 4; i++)
#pragma unroll
        for (int j = 0; j < 4; j++) acc[i][j] = (f32x4){0.f, 0.f, 0.f, 0.f};

    for (int k0 = 0; k0 < 512; k0 += 64) {
#pragma unroll
        for (int i = 0; i < 4; i++) {
            int cid = tid + i * 256;
            int r = cid >> 3, c8 = cid & 7;
            if (CVT) {
                const float* ap = Af + (size_t)(row0 + r) * 512 + k0 + c8 * 8;
                float4 f0 = *reinterpret_cast<const float4*>(ap);
                float4 f1 = *reinterpret_cast<const float4*>(ap + 4);
                union { ushort_t s[8]; uint4 u; } pk;
                pk.s[0] = f2bf(f0.x); pk.s[1] = f2bf(f0.y); pk.s[2] = f2bf(f0.z); pk.s[3] = f2bf(f0.w);
                pk.s[4] = f2bf(f1.x); pk.s[5] = f2bf(f1.y); pk.s[6] = f2bf(f1.z); pk.s[7] = f2bf(f1.w);
                *reinterpret_cast<uint4*>(&smem[0][r][c8 * 8]) = pk.u;
            } else {
                *reinterpret_cast<uint4*>(&smem[0][r][c8 * 8]) =
                    *reinterpret_cast<const uint4*>(Ab + (size_t)(row0 + r) * 512 + k0 + c8 * 8);
            }
            *reinterpret_cast<uint4*>(&smem[1][r][c8 * 8]) =
                *reinterpret_cast<const uint4*>(Bt + (size_t)(col0 + r) * 512 + k0 + c8 * 8);
        }
        __syncthreads();
#pragma unroll
        for (int kc = 0; kc < 2; kc++) {
            bf16x8 af[4], bg[4];
#pragma unroll
            for (int m = 0; m < 4; m++)
                af[m] = load8(&smem[0][wr * 64 + m * 16 + l16][kc * 32 + quad * 8]);
#pragma unroll
            for (int n = 0; n < 4; n++)
                bg[n] = load8(&smem[1][wc * 64 + n * 16 + l16][kc * 32 + quad * 8]);
#pragma unroll
            for (int m = 0; m < 4; m++)
#pragma unroll
                for (int n = 0; n < 4; n++)
                    acc[m][n] = __builtin_amdgcn_mfma_f32_16x16x32_bf16(af[m], bg[n], acc[m][n], 0, 0, 0);
        }
        __syncthreads();
    }

    if (z == 3) {
        ushort_t (*Ts)[130] = reinterpret_cast<ushort_t(*)[130]>(&smem[0][0][0]);
#pragma unroll
        for (int m = 0; m < 4; m++)
#pragma unroll
            for (int n = 0; n < 4; n++) {
                int dl = wc * 64 + n * 16 + l16;
                float bcol = bv[col0 + dl];
#pragma unroll
                for (int r = 0; r < 4; r++) {
                    int sl = wr * 64 + m * 16 + quad * 4 + r;
                    Ts[dl][sl] = f2bf(acc[m][n][r] + bcol);
                }
            }
        __syncthreads();
        int b_ = row0 >> 10, s0 = row0 & 1023;
#pragma unroll
        for (int p = 0; p < 8; p++) {
            int dl = p * 16 + (tid >> 4);
            int sl = (tid & 15) * 8;
            int col = col0 + dl, h_ = col >> 6, d_ = col & 63;
            ushort_t* dst = Vt + (((size_t)(b_ * 8 + h_)) * 64 + d_) * 1024 + s0 + sl;
            union { uint4 u; ushort_t s[8]; } pk;
#pragma unroll
            for (int e = 0; e < 8; e++) pk.s[e] = Ts[dl][sl + e];
            *reinterpret_cast<uint4*>(dst) = pk.u;
        }
    } else {
#pragma unroll
        for (int m = 0; m < 4; m++)
#pragma unroll
            for (int n = 0; n < 4; n++) {
                int col = col0 + wc * 64 + n * 16 + l16;
                float bcol = bias ? bias[col] : 0.f;
#pragma unroll
                for (int r = 0; r < 4; r++) {
                    int row = row0 + wr * 64 + m * 16 + quad * 4 + r;
                    float val = acc[m][n][r] + bcol;
                    int b_ = row >> 10, s_ = row & 1023, h_ = col >> 6, d_ = col & 63;
                    size_t idx = (((size_t)(b_ * 8 + h_)) * 1024 + s_) * 64 + d_;
                    if (z == 0) {
                        Qu[idx] = f2bf(val + ub[col]);
                        Qv[idx] = f2bf(val + vb[col]);
                    } else {
                        (z == 1 ? Kp : Pp)[idx] = f2bf(val);
                    }
                }
            }
    }
}

// ---------------------------------------------------------------------------
// out-proj: ctx[8192x512]bf16 @ Wo^T + bo -> fp32 out. 128x64 tiles, 512 blk.
// ---------------------------------------------------------------------------
__global__ __launch_bounds__(256) void out_gemm(
    const ushort_t* __restrict__ A, const ushort_t* __restrict__ Bt,
    const float* __restrict__ bias, float* __restrict__ outf) {
    __shared__ ushort_t As[128][72];
    __shared__ ushort_t Bs[64][72];
    int tid = threadIdx.x;
    int wid = tid >> 6, lane = tid & 63, quad = lane >> 4, l16 = lane & 15;
    int row0 = blockIdx.y * 128, col0 = blockIdx.x * 64;

    f32x4 acc[2][4];
#pragma unroll
    for (int i = 0; i < 2; i++)
#pragma unroll
        for (int j = 0; j < 4; j++) acc[i][j] = (f32x4){0.f, 0.f, 0.f, 0.f};

    for (int k0 = 0; k0 < 512; k0 += 64) {
#pragma unroll
        for (int i = 0; i < 4; i++) {
            int cid = tid + i * 256;
            int r = cid >> 3, c8 = cid & 7;
            *reinterpret_cast<uint4*>(&As[r][c8 * 8]) =
                *reinterpret_cast<const uint4*>(A + (size_t)(row0 + r) * 512 + k0 + c8 * 8);
        }
#pragma unroll
        for (int i = 0; i < 2; i++) {
            int cid = tid + i * 256;
            int r = cid >> 3, c8 = cid & 7;
            *reinterpret_cast<uint4*>(&Bs[r][c8 * 8]) =
                *reinterpret_cast<const uint4*>(Bt + (size_t)(col0 + r) * 512 + k0 + c8 * 8);
        }
        __syncthreads();
#pragma unroll
        for (int kc = 0; kc < 2; kc++) {
            bf16x8 af[2], bg[4];
#pragma unroll
            for (int m = 0; m < 2; m++)
                af[m] = load8(&As[wid * 32 + m * 16 + l16][kc * 32 + quad * 8]);
#pragma unroll
            for (int n = 0; n < 4; n++)
                bg[n] = load8(&Bs[n * 16 + l16][kc * 32 + quad * 8]);
#pragma unroll
            for (int m = 0; m < 2; m++)
#pragma unroll
                for (int n = 0; n < 4; n++)
                    acc[m][n] = __builtin_amdgcn_mfma_f32_16x16x32_bf16(af[m], bg[n], acc[m][n], 0, 0, 0);
        }
        __syncthreads();
    }
#pragma unroll
    for (int m = 0; m < 2; m++)
#pragma unroll
        for (int n = 0; n < 4; n++) {
            int col = col0 + n * 16 + l16;
#pragma unroll
            for (int r = 0; r < 4; r++) {
                int row = row0 + wid * 32 + m * 16 + quad * 4 + r;
                outf[(size_t)row * 512 + col] = acc[m][n][r] + bias[col];
            }
        }
}

// ---------------------------------------------------------------------------
// pos window pass: MFMA over sliding P windows, scatter-write into sc.
// k(element r) = wt + kbb + (quad*4+r) + l16 ; guarded to [kw0,kw1) and
// col (wt+l16) <= collim (branch1: S-1 => k<=q ; branch2: +inf).
// Interior windows take the unguarded fast path. Depth-2 global prefetch.
// ---------------------------------------------------------------------------
__device__ __forceinline__ void pos_pass(
    const ushort_t* __restrict__ P_b, ushort_t (*sc)[1032],
    const bf16x8* av, int wlo, int whi, int kbb, int collim, int mtrow,
    int kw0, int kw1, int quad, int l16) {
    if (whi < wlo) return;
    int nw = (whi - wlo) / 16 + 1;
    bf16x8 pb0[2], pb1[2];
#pragma unroll
    for (int i = 0; i < 2; i++) {
        if (i < nw) {
            int pr = wlo + i * 16 + l16; if (pr > S_LEN - 1) pr = S_LEN - 1;
            pb0[i] = load8(P_b + (size_t)pr * 64 + quad * 8);
            pb1[i] = load8(P_b + (size_t)pr * 64 + 32 + quad * 8);
        }
    }
    for (int w = 0; w < nw; w++) {
        int cur = w & 1;
        bf16x8 b0 = pb0[cur], b1 = pb1[cur];
        if (w + 2 < nw) {
            int pr = wlo + (w + 2) * 16 + l16; if (pr > S_LEN - 1) pr = S_LEN - 1;
            pb0[cur] = load8(P_b + (size_t)pr * 64 + quad * 8);
            pb1[cur] = load8(P_b + (size_t)pr * 64 + 32 + quad * 8);
        }
        f32x4 acc = (f32x4){0.f, 0.f, 0.f, 0.f};
        acc = __builtin_amdgcn_mfma_f32_16x16x32_bf16(av[0], b0, acc, 0, 0, 0);
        acc = __builtin_amdgcn_mfma_f32_16x16x32_bf16(av[1], b1, acc, 0, 0, 0);
        int wt = wlo + w * 16;
        int kb = wt + kbb;
        if (kb >= kw0 && kb + 30 < kw1 && wt + 15 <= collim) {
#pragma unroll
            for (int r = 0; r < 4; r++) {
                int m = quad * 4 + r;
                sc[mtrow + m][kb + m + l16] = f2bf(acc[r]);
            }
        } else {
#pragma unroll
            for (int r = 0; r < 4; r++) {
                int m = quad * 4 + r;
                int k = kb + m + l16;
                if (k >= kw0 && k < kw1 && (wt + l16) <= collim)
                    sc[mtrow + m][k] = f2bf(acc[r]);
            }
        }
    }
}

// ---------------------------------------------------------------------------
// Fused attention v4: 32 q-rows/block, 4 waves x 256-k, depth-2 prefetch
// everywhere, interior-window fast path, shared K/V loads feed 2 m-tiles.
// ---------------------------------------------------------------------------
__global__ __launch_bounds__(256) void attn_kernel(
    const ushort_t* __restrict__ Qu, const ushort_t* __restrict__ Qv,
    const ushort_t* __restrict__ Kp, const ushort_t* __restrict__ Pp,
    const ushort_t* __restrict__ Vt, ushort_t* __restrict__ ctxb) {
    __shared__ ushort_t sc[32][1032];
    __shared__ float red1[4][32];
    __shared__ float red2[32][8];
    __shared__ float rowinv[32];

    constexpr float SCL = (float)(1.4426950408889634 / 22.627416997969522);

    int bx = blockIdx.x;
    int bh = bx >> 5, q0 = (bx & 31) << 5;
    int tid = threadIdx.x, wid = tid >> 6, lane = tid & 63;
    int quad = lane >> 4, l16 = lane & 15;

    const ushort_t* Qu_b = Qu + (size_t)bh * S_LEN * DHEAD;
    const ushort_t* Qv_b = Qv + (size_t)bh * S_LEN * DHEAD;
    const ushort_t* K_b  = Kp + (size_t)bh * S_LEN * DHEAD;
    const ushort_t* P_b  = Pp + (size_t)bh * S_LEN * DHEAD;
    const ushort_t* V_b  = Vt + (size_t)bh * DHEAD * S_LEN;

    int kw0 = wid << 8, kw1 = kw0 + 256;
    int d0 = wid << 4;

    // hoisted loads: Q frags, K first windows, V first chunk
    bf16x8 au0[2], au1[2], av1[2][2], av2[2][2];
#pragma unroll
    for (int kc = 0; kc < 2; kc++) {
        au0[kc] = load8(Qu_b + (size_t)(q0 + l16) * 64 + kc * 32 + quad * 8);
        au1[kc] = load8(Qu_b + (size_t)(q0 + 16 + l16) * 64 + kc * 32 + quad * 8);
#pragma unroll
        for (int mt = 0; mt < 2; mt++) {
            int q0m = q0 + mt * 16;
            av1[mt][kc] = load8(Qv_b + (size_t)(q0m + l16) * 64 + kc * 32 + quad * 8);
            int r2 = q0m + 1 + l16; if (r2 > S_LEN - 1) r2 = S_LEN - 1;
            av2[mt][kc] = load8(Qv_b + (size_t)r2 * 64 + kc * 32 + quad * 8);
        }
    }
    const ushort_t* Kw = K_b + (size_t)kw0 * 64;
    bf16x8 kb0[2], kb1[2];
#pragma unroll
    for (int i = 0; i < 2; i++) {
        kb0[i] = load8(Kw + (size_t)(i * 16 + l16) * 64 + quad * 8);
        kb1[i] = load8(Kw + (size_t)(i * 16 + l16) * 64 + 32 + quad * 8);
    }
    const ushort_t* Vw = V_b + (size_t)(d0 + l16) * 1024;
    bf16x8 vv[2];
    vv[0] = load8(Vw + quad * 8);
    vv[1] = load8(Vw + 32 + quad * 8);

    // zero-fill k = q+1 inside this wave's range
    if (lane < 32) {
        int kz = q0 + lane + 1;
        if (kz >= kw0 && kz < kw1) sc[lane][kz] = 0;
    }

    // ---- pos scores ----
#pragma unroll
    for (int mt = 0; mt < 2; mt++) {
        int q0m = q0 + mt * 16;
        int wlo = (S_LEN - 16) - q0m + kw0;
        int d1 = kw1 - 1 - q0m; if (d1 > 0) d1 = 0;
        int whi = (S_LEN - 1) + d1;
        pos_pass(P_b, sc, av1[mt], wlo, whi, q0m - (S_LEN - 1), S_LEN - 1,
                 mt * 16, kw0, kw1, quad, l16);
        int wlo2 = kw0 - q0m - 17; if (wlo2 < 0) wlo2 = 0;
        int whi2 = kw1 - 3 - q0m;
        pos_pass(P_b, sc, av2[mt], wlo2, whi2, q0m + 2, 1 << 30,
                 mt * 16, kw0, kw1, quad, l16);
    }

    // ---- content pass: K tile feeds both m-tiles; C = pos from LDS ----
    float pm0[4] = {-1e30f, -1e30f, -1e30f, -1e30f};
    float pm1[4] = {-1e30f, -1e30f, -1e30f, -1e30f};
    for (int nt = 0; nt < 16; ++nt) {
        int cur = nt & 1;
        bf16x8 b0 = kb0[cur], b1 = kb1[cur];
        if (nt + 2 < 16) {
            const ushort_t* kp = Kw + (size_t)((nt + 2) * 16 + l16) * 64;
            kb0[cur] = load8(kp + quad * 8);
            kb1[cur] = load8(kp + 32 + quad * 8);
        }
        int kt = kw0 + nt * 16;
        f32x4 a0, a1;
#pragma unroll
        for (int r = 0; r < 4; r++) {
            a0[r] = bf2f(sc[quad * 4 + r][kt + l16]);
            a1[r] = bf2f(sc[16 + quad * 4 + r][kt + l16]);
        }
        a0 = __builtin_amdgcn_mfma_f32_16x16x32_bf16(au0[0], b0, a0, 0, 0, 0);
        a0 = __builtin_amdgcn_mfma_f32_16x16x32_bf16(au0[1], b1, a0, 0, 0, 0);
        a1 = __builtin_amdgcn_mfma_f32_16x16x32_bf16(au1[0], b0, a1, 0, 0, 0);
        a1 = __builtin_amdgcn_mfma_f32_16x16x32_bf16(au1[1], b1, a1, 0, 0, 0);
#pragma unroll
        for (int r = 0; r < 4; r++) {
            sc[quad * 4 + r][kt + l16] = f2bf(a0[r]);
            sc[16 + quad * 4 + r][kt + l16] = f2bf(a1[r]);
            pm0[r] = fmaxf(pm0[r], a0[r]);
            pm1[r] = fmaxf(pm1[r], a1[r]);
        }
    }
#pragma unroll
    for (int off = 1; off < 16; off <<= 1)
#pragma unroll
        for (int r = 0; r < 4; r++) {
            pm0[r] = fmaxf(pm0[r], __shfl_xor(pm0[r], off));
            pm1[r] = fmaxf(pm1[r], __shfl_xor(pm1[r], off));
        }
    if (l16 == 0) {
#pragma unroll
        for (int r = 0; r < 4; r++) {
            red1[wid][quad * 4 + r] = pm0[r];
            red1[wid][16 + quad * 4 + r] = pm1[r];
        }
    }
    __syncthreads();   // B1

    // ---- softmax: thread (row=tid&31, cb=tid>>5) owns cols [cb*128,+128) ----
    int row = tid & 31, cb = tid >> 5;
    float rm = fmaxf(fmaxf(red1[0][row], red1[1][row]), fmaxf(red1[2][row], red1[3][row]));
    float ssum = 0.f;
    ushort_t* sp = &sc[row][cb * 128];
#pragma unroll
    for (int j = 0; j < 16; j++) {
        union { uint4 u; ushort_t s[8]; } in, out;
        in.u = *reinterpret_cast<uint4*>(sp + j * 8);
#pragma unroll
        for (int e = 0; e < 8; e++) {
            float ev = exp2f((bf2f(in.s[e]) - rm) * SCL);
            out.s[e] = f2bf(ev);
            ssum += ev;
        }
        *reinterpret_cast<uint4*>(sp + j * 8) = out.u;
    }
    red2[row][cb] = ssum;
    __syncthreads();   // B2
    if (tid < 32) {
        float s = 0.f;
#pragma unroll
        for (int c = 0; c < 8; c++) s += red2[tid][c];
        rowinv[tid] = 1.0f / s;
    }

    // ---- PV: wave owns d-cols [16w,+16); depth-2 V prefetch ----
    f32x4 ac0 = (f32x4){0.f, 0.f, 0.f, 0.f};
    f32x4 ac1 = (f32x4){0.f, 0.f, 0.f, 0.f};
    for (int kc = 0; kc < 32; ++kc) {
        bf16x8 b = vv[kc & 1];
        if (kc + 2 < 32) vv[kc & 1] = load8(Vw + (kc + 2) * 32 + quad * 8);
        bf16x8 a0 = load8(&sc[l16][kc * 32 + quad * 8]);
        bf16x8 a1 = load8(&sc[16 + l16][kc * 32 + quad * 8]);
        ac0 = __builtin_amdgcn_mfma_f32_16x16x32_bf16(a0, b, ac0, 0, 0, 0);
        ac1 = __builtin_amdgcn_mfma_f32_16x16x32_bf16(a1, b, ac1, 0, 0, 0);
    }
    __syncthreads();   // B3 (rowinv visibility)
    int b_ = bh >> 3, h_ = bh & 7;
#pragma unroll
    for (int r = 0; r < 4; r++) {
        int m = quad * 4 + r;
        ctxb[((size_t)b_ * 1024 + (q0 + m)) * 512 + h_ * 64 + d0 + l16] =
            f2bf(ac0[r] * rowinv[m]);
        ctxb[((size_t)b_ * 1024 + (q0 + 16 + m)) * 512 + h_ * 64 + d0 + l16] =
            f2bf(ac1[r] * rowinv[16 + m]);
    }
}

extern "C" void kernel_launch(void* const* d_in, const int* in_sizes, int n_in,
                              void* d_out, int out_size, void* d_ws, size_t ws_size,
                              hipStream_t stream) {
    const float* q  = (const float*)d_in[0];
    const float* k  = (const float*)d_in[1];
    const float* v  = (const float*)d_in[2];
    const float* pe = (const float*)d_in[3];
    const float* Wq = (const float*)d_in[4];
    const float* bq = (const float*)d_in[5];
    const float* Wk = (const float*)d_in[6];
    const float* bk = (const float*)d_in[7];
    const float* Wv = (const float*)d_in[8];
    const float* bv = (const float*)d_in[9];
    const float* Wp = (const float*)d_in[10];
    const float* ub = (const float*)d_in[11];
    const float* vbias = (const float*)d_in[12];
    const float* Wo = (const float*)d_in[13];
    const float* bo = (const float*)d_in[14];
    float* out = (float*)d_out;
    ushort_t* ws = (ushort_t*)d_ws;

    ushort_t* wT  = ws;                       // 5 x 262144 = 1,310,720
    ushort_t* Qu  = ws + 1310720;
    ushort_t* Qv  = Qu + 4194304;
    ushort_t* Kp  = Qv + 4194304;
    ushort_t* Pp  = Kp + 4194304;
    ushort_t* Vt  = Pp + 4194304;
    ushort_t* actb = Vt + 4194304;            // big path: 4 x 4,194,304
    ushort_t* ctx_big = actb;                 // alias act[0]: dead after proj

    const size_t need_big = (size_t)(1310720 + 9 * 4194304) * 2;  // ~78.1 MB
    bool big = ws_size >= need_big;

    prep_w<<<dim3(8, 8, 5), 256, 0, stream>>>(Wq, Wk, Wv, Wp, Wo, wT);
    if (big) {
        prep_act<<<dim3(4096, 4), 256, 0, stream>>>(q, k, v, pe, actb);
        proj_gemm<0><<<dim3(4, 64, 4), 256, 0, stream>>>(q, k, v, pe, actb, wT,
            bq, bk, bv, ub, vbias, Qu, Qv, Kp, Pp, Vt);
        attn_kernel<<<2048, 256, 0, stream>>>(Qu, Qv, Kp, Pp, Vt, ctx_big);
        out_gemm<<<dim3(8, 64), 256, 0, stream>>>(ctx_big, wT + 4 * 262144, bo, out);
    } else {
        // fallback: ctx lives after Vt (R3 layout, ~53 MB)
        ushort_t* ctx = actb;
        proj_gemm<1><<<dim3(4, 64, 4), 256, 0, stream>>>(q, k, v, pe, nullptr, wT,
            bq, bk, bv, ub, vbias, Qu, Qv, Kp, Pp, Vt);
        attn_kernel<<<2048, 256, 0, stream>>>(Qu, Qv, Kp, Pp, Vt, ctx);
        out_gemm<<<dim3(8, 64), 256, 0, stream>>>(ctx, wT + 4 * 262144, bo, out);
    }
}

// Round 5
// 328.144 us; speedup vs baseline: 2.4110x; 2.4110x over previous
//
#include <hip/hip_runtime.h>
#include <cstdint>

typedef unsigned short ushort_t;
typedef __attribute__((ext_vector_type(8))) short bf16x8;
typedef __attribute__((ext_vector_type(4))) float f32x4;

#define S_LEN 1024
#define DHEAD 64

__device__ inline ushort_t f2bf(float f) {
    union { float f; uint32_t u; } c; c.f = f;
    uint32_t u = c.u;
    uint32_t r = u + 0x7FFFu + ((u >> 16) & 1u);
    return (ushort_t)(r >> 16);
}
__device__ inline float bf2f(ushort_t h) {
    union { uint32_t u; float f; } c; c.u = ((uint32_t)h) << 16;
    return c.f;
}
__device__ inline bf16x8 load8(const ushort_t* p) {
    union { uint4 u; bf16x8 v; } c;
    c.u = *reinterpret_cast<const uint4*>(p);
    return c.v;
}

// ---------------------------------------------------------------------------
// prep_w: tiled transpose+convert 5 weights (512x512) fp32 -> bf16 W^T
// ---------------------------------------------------------------------------
__global__ __launch_bounds__(256) void prep_w(
    const float* __restrict__ wq, const float* __restrict__ wk,
    const float* __restrict__ wv, const float* __restrict__ wp,
    const float* __restrict__ wo, ushort_t* __restrict__ ws) {
    __shared__ float tile[64][65];
    int wi = blockIdx.z;
    const float* src = wi == 0 ? wq : wi == 1 ? wk : wi == 2 ? wv : wi == 3 ? wp : wo;
    int cx = blockIdx.x * 64, ry = blockIdx.y * 64;
    int t = threadIdx.x;
    int tr = t >> 4, tc = (t & 15) * 4;
#pragma unroll
    for (int i = 0; i < 4; i++) {
        int r = tr + i * 16;
        float4 f = *reinterpret_cast<const float4*>(src + (size_t)(ry + r) * 512 + cx + tc);
        tile[r][tc] = f.x; tile[r][tc + 1] = f.y; tile[r][tc + 2] = f.z; tile[r][tc + 3] = f.w;
    }
    __syncthreads();
    ushort_t* dst = ws + (size_t)wi * 262144;
#pragma unroll
    for (int i = 0; i < 4; i++) {
        int r = tr + i * 16;
        ushort4 o;
        o.x = f2bf(tile[tc][r]); o.y = f2bf(tile[tc + 1][r]);
        o.z = f2bf(tile[tc + 2][r]); o.w = f2bf(tile[tc + 3][r]);
        *reinterpret_cast<ushort4*>(dst + (size_t)(cx + r) * 512 + ry + tc) = o;
    }
}

// ---------------------------------------------------------------------------
// prep_act: elementwise fp32 -> bf16 for the 4 activations (8192x512 each)
// ---------------------------------------------------------------------------
__global__ __launch_bounds__(256) void prep_act(
    const float* __restrict__ q, const float* __restrict__ k,
    const float* __restrict__ v, const float* __restrict__ p,
    ushort_t* __restrict__ actb) {
    int t = blockIdx.x * 256 + threadIdx.x;   // 0..1048575
    int sec = blockIdx.y;
    const float* src = sec == 0 ? q : sec == 1 ? k : sec == 2 ? v : p;
    ushort_t* dst = actb + (size_t)sec * 4194304;
    float4 f = reinterpret_cast<const float4*>(src)[t];
    ushort4 o;
    o.x = f2bf(f.x); o.y = f2bf(f.y); o.z = f2bf(f.z); o.w = f2bf(f.w);
    *reinterpret_cast<ushort4*>(dst + (size_t)t * 4) = o;
}

// ---------------------------------------------------------------------------
// merged projection GEMM: z=0 Q (->Qu,Qv), z=1 K (->Kp), z=2 P (->Pp),
// z=3 V (->Vt transposed [bh][dh][s]). CVT=1: A fp32, convert during staging.
// CVT=0: A bf16 from pre-converted act buffer.
// ---------------------------------------------------------------------------
template<int CVT>
__global__ __launch_bounds__(256) void proj_gemm(
    const float* __restrict__ qa, const float* __restrict__ ka,
    const float* __restrict__ va, const float* __restrict__ pa,
    const ushort_t* __restrict__ actb,
    const ushort_t* __restrict__ wT,
    const float* __restrict__ bq, const float* __restrict__ bk,
    const float* __restrict__ bv,
    const float* __restrict__ ub, const float* __restrict__ vb,
    ushort_t* __restrict__ Qu, ushort_t* __restrict__ Qv,
    ushort_t* __restrict__ Kp, ushort_t* __restrict__ Pp,
    ushort_t* __restrict__ Vt) {
    __shared__ ushort_t smem[2][128][72];
    int z = blockIdx.z;
    const float* Af = z == 0 ? qa : z == 1 ? ka : z == 2 ? pa : va;
    const ushort_t* Ab = actb + (size_t)(z == 0 ? 0 : z == 1 ? 1 : z == 2 ? 3 : 2) * 4194304;
    const ushort_t* Bt = wT + (z == 0 ? 0 : z == 1 ? 262144 : z == 2 ? 786432 : 524288);
    const float* bias = z == 0 ? bq : z == 1 ? bk : z == 3 ? bv : nullptr;

    int tid = threadIdx.x;
    int wid = tid >> 6, lane = tid & 63, quad = lane >> 4, l16 = lane & 15;
    int wr = wid >> 1, wc = wid & 1;
    int row0 = blockIdx.y * 128, col0 = blockIdx.x * 128;

    f32x4 acc[4][4];
#pragma unroll
    for (int i = 0; i < 4; i++)
#pragma unroll
        for (int j = 0; j < 4; j++) acc[i][j] = (f32x4){0.f, 0.f, 0.f, 0.f};

    for (int k0 = 0; k0 < 512; k0 += 64) {
#pragma unroll
        for (int i = 0; i < 4; i++) {
            int cid = tid + i * 256;
            int r = cid >> 3, c8 = cid & 7;
            if (CVT) {
                const float* ap = Af + (size_t)(row0 + r) * 512 + k0 + c8 * 8;
                float4 f0 = *reinterpret_cast<const float4*>(ap);
                float4 f1 = *reinterpret_cast<const float4*>(ap + 4);
                union { ushort_t s[8]; uint4 u; } pk;
                pk.s[0] = f2bf(f0.x); pk.s[1] = f2bf(f0.y); pk.s[2] = f2bf(f0.z); pk.s[3] = f2bf(f0.w);
                pk.s[4] = f2bf(f1.x); pk.s[5] = f2bf(f1.y); pk.s[6] = f2bf(f1.z); pk.s[7] = f2bf(f1.w);
                *reinterpret_cast<uint4*>(&smem[0][r][c8 * 8]) = pk.u;
            } else {
                *reinterpret_cast<uint4*>(&smem[0][r][c8 * 8]) =
                    *reinterpret_cast<const uint4*>(Ab + (size_t)(row0 + r) * 512 + k0 + c8 * 8);
            }
            *reinterpret_cast<uint4*>(&smem[1][r][c8 * 8]) =
                *reinterpret_cast<const uint4*>(Bt + (size_t)(col0 + r) * 512 + k0 + c8 * 8);
        }
        __syncthreads();
#pragma unroll
        for (int kc = 0; kc < 2; kc++) {
            bf16x8 af[4], bg[4];
#pragma unroll
            for (int m = 0; m < 4; m++)
                af[m] = load8(&smem[0][wr * 64 + m * 16 + l16][kc * 32 + quad * 8]);
#pragma unroll
            for (int n = 0; n < 4; n++)
                bg[n] = load8(&smem[1][wc * 64 + n * 16 + l16][kc * 32 + quad * 8]);
#pragma unroll
            for (int m = 0; m < 4; m++)
#pragma unroll
                for (int n = 0; n < 4; n++)
                    acc[m][n] = __builtin_amdgcn_mfma_f32_16x16x32_bf16(af[m], bg[n], acc[m][n], 0, 0, 0);
        }
        __syncthreads();
    }

    if (z == 3) {
        ushort_t (*Ts)[130] = reinterpret_cast<ushort_t(*)[130]>(&smem[0][0][0]);
#pragma unroll
        for (int m = 0; m < 4; m++)
#pragma unroll
            for (int n = 0; n < 4; n++) {
                int dl = wc * 64 + n * 16 + l16;
                float bcol = bv[col0 + dl];
#pragma unroll
                for (int r = 0; r < 4; r++) {
                    int sl = wr * 64 + m * 16 + quad * 4 + r;
                    Ts[dl][sl] = f2bf(acc[m][n][r] + bcol);
                }
            }
        __syncthreads();
        int b_ = row0 >> 10, s0 = row0 & 1023;
#pragma unroll
        for (int p = 0; p < 8; p++) {
            int dl = p * 16 + (tid >> 4);
            int sl = (tid & 15) * 8;
            int col = col0 + dl, h_ = col >> 6, d_ = col & 63;
            ushort_t* dst = Vt + (((size_t)(b_ * 8 + h_)) * 64 + d_) * 1024 + s0 + sl;
            union { uint4 u; ushort_t s[8]; } pk;
#pragma unroll
            for (int e = 0; e < 8; e++) pk.s[e] = Ts[dl][sl + e];
            *reinterpret_cast<uint4*>(dst) = pk.u;
        }
    } else {
#pragma unroll
        for (int m = 0; m < 4; m++)
#pragma unroll
            for (int n = 0; n < 4; n++) {
                int col = col0 + wc * 64 + n * 16 + l16;
                float bcol = bias ? bias[col] : 0.f;
#pragma unroll
                for (int r = 0; r < 4; r++) {
                    int row = row0 + wr * 64 + m * 16 + quad * 4 + r;
                    float val = acc[m][n][r] + bcol;
                    int b_ = row >> 10, s_ = row & 1023, h_ = col >> 6, d_ = col & 63;
                    size_t idx = (((size_t)(b_ * 8 + h_)) * 1024 + s_) * 64 + d_;
                    if (z == 0) {
                        Qu[idx] = f2bf(val + ub[col]);
                        Qv[idx] = f2bf(val + vb[col]);
                    } else {
                        (z == 1 ? Kp : Pp)[idx] = f2bf(val);
                    }
                }
            }
    }
}

// ---------------------------------------------------------------------------
// out-proj: ctx[8192x512]bf16 @ Wo^T + bo -> fp32 out. 128x64 tiles, 512 blk.
// ---------------------------------------------------------------------------
__global__ __launch_bounds__(256) void out_gemm(
    const ushort_t* __restrict__ A, const ushort_t* __restrict__ Bt,
    const float* __restrict__ bias, float* __restrict__ outf) {
    __shared__ ushort_t As[128][72];
    __shared__ ushort_t Bs[64][72];
    int tid = threadIdx.x;
    int wid = tid >> 6, lane = tid & 63, quad = lane >> 4, l16 = lane & 15;
    int row0 = blockIdx.y * 128, col0 = blockIdx.x * 64;

    f32x4 acc[2][4];
#pragma unroll
    for (int i = 0; i < 2; i++)
#pragma unroll
        for (int j = 0; j < 4; j++) acc[i][j] = (f32x4){0.f, 0.f, 0.f, 0.f};

    for (int k0 = 0; k0 < 512; k0 += 64) {
#pragma unroll
        for (int i = 0; i < 4; i++) {
            int cid = tid + i * 256;
            int r = cid >> 3, c8 = cid & 7;
            *reinterpret_cast<uint4*>(&As[r][c8 * 8]) =
                *reinterpret_cast<const uint4*>(A + (size_t)(row0 + r) * 512 + k0 + c8 * 8);
        }
#pragma unroll
        for (int i = 0; i < 2; i++) {
            int cid = tid + i * 256;
            int r = cid >> 3, c8 = cid & 7;
            *reinterpret_cast<uint4*>(&Bs[r][c8 * 8]) =
                *reinterpret_cast<const uint4*>(Bt + (size_t)(col0 + r) * 512 + k0 + c8 * 8);
        }
        __syncthreads();
#pragma unroll
        for (int kc = 0; kc < 2; kc++) {
            bf16x8 af[2], bg[4];
#pragma unroll
            for (int m = 0; m < 2; m++)
                af[m] = load8(&As[wid * 32 + m * 16 + l16][kc * 32 + quad * 8]);
#pragma unroll
            for (int n = 0; n < 4; n++)
                bg[n] = load8(&Bs[n * 16 + l16][kc * 32 + quad * 8]);
#pragma unroll
            for (int m = 0; m < 2; m++)
#pragma unroll
                for (int n = 0; n < 4; n++)
                    acc[m][n] = __builtin_amdgcn_mfma_f32_16x16x32_bf16(af[m], bg[n], acc[m][n], 0, 0, 0);
        }
        __syncthreads();
    }
#pragma unroll
    for (int m = 0; m < 2; m++)
#pragma unroll
        for (int n = 0; n < 4; n++) {
            int col = col0 + n * 16 + l16;
#pragma unroll
            for (int r = 0; r < 4; r++) {
                int row = row0 + wid * 32 + m * 16 + quad * 4 + r;
                outf[(size_t)row * 512 + col] = acc[m][n][r] + bias[col];
            }
        }
}

// one pos window: 2 MFMA + sheared scatter-write (fast path when interior)
#define POS_EMIT(B0_, B1_, WT_) do {                                          \
    f32x4 acc_ = (f32x4){0.f, 0.f, 0.f, 0.f};                                 \
    acc_ = __builtin_amdgcn_mfma_f32_16x16x32_bf16(av[0], (B0_), acc_, 0, 0, 0); \
    acc_ = __builtin_amdgcn_mfma_f32_16x16x32_bf16(av[1], (B1_), acc_, 0, 0, 0); \
    int kb_ = (WT_) + kbb;                                                    \
    if (kb_ >= kw0 && kb_ + 30 < kw1 && (WT_) + 15 <= collim) {               \
        _Pragma("unroll") for (int r_ = 0; r_ < 4; r_++) {                    \
            int m_ = quad * 4 + r_;                                           \
            sc[mtrow + m_][kb_ + m_ + l16] = f2bf(acc_[r_]);                  \
        }                                                                     \
    } else {                                                                  \
        _Pragma("unroll") for (int r_ = 0; r_ < 4; r_++) {                    \
            int m_ = quad * 4 + r_;                                           \
            int k_ = kb_ + m_ + l16;                                          \
            if (k_ >= kw0 && k_ < kw1 && ((WT_) + l16) <= collim)             \
                sc[mtrow + m_][k_] = f2bf(acc_[r_]);                          \
        }                                                                     \
    }                                                                         \
} while (0)

// ---------------------------------------------------------------------------
// pos window pass: unroll-by-2 software pipeline with NAMED register pairs
// (no dynamically-indexed register arrays -> no scratch/cndmask storm).
// Use-then-reload order gives true depth-2 latency hiding.
// ---------------------------------------------------------------------------
__device__ __forceinline__ void pos_pass(
    const ushort_t* __restrict__ P_b, ushort_t (*sc)[1032],
    const bf16x8* av, int wlo, int whi, int kbb, int collim, int mtrow,
    int kw0, int kw1, int quad, int l16) {
    if (whi < wlo) return;
    int nw = (whi - wlo) / 16 + 1;
    bf16x8 A0, A1, B0, B1;
    {
        int pr = wlo + l16; if (pr > S_LEN - 1) pr = S_LEN - 1;
        A0 = load8(P_b + (size_t)pr * 64 + quad * 8);
        A1 = load8(P_b + (size_t)pr * 64 + 32 + quad * 8);
    }
    if (nw > 1) {
        int pr = wlo + 16 + l16; if (pr > S_LEN - 1) pr = S_LEN - 1;
        B0 = load8(P_b + (size_t)pr * 64 + quad * 8);
        B1 = load8(P_b + (size_t)pr * 64 + 32 + quad * 8);
    }
    int w = 0;
    for (; w + 1 < nw; w += 2) {
        int wtA = wlo + w * 16;
        POS_EMIT(A0, A1, wtA);
        if (w + 2 < nw) {
            int pr = wtA + 32 + l16; if (pr > S_LEN - 1) pr = S_LEN - 1;
            A0 = load8(P_b + (size_t)pr * 64 + quad * 8);
            A1 = load8(P_b + (size_t)pr * 64 + 32 + quad * 8);
        }
        int wtB = wtA + 16;
        POS_EMIT(B0, B1, wtB);
        if (w + 3 < nw) {
            int pr = wtB + 32 + l16; if (pr > S_LEN - 1) pr = S_LEN - 1;
            B0 = load8(P_b + (size_t)pr * 64 + quad * 8);
            B1 = load8(P_b + (size_t)pr * 64 + 32 + quad * 8);
        }
    }
    if (w < nw) {
        int wt = wlo + w * 16;
        POS_EMIT(A0, A1, wt);
    }
}

// ---------------------------------------------------------------------------
// Fused attention v5: 32 q-rows/block, 4 waves x 256-k. R3 structure +
// named-var pipelined pos, fully-unrolled content/PV (compiler schedules
// vmcnt), XCD-aware bh swizzle (8 bh per XCD -> K/P/V fit 4MB L2).
// ---------------------------------------------------------------------------
__global__ __launch_bounds__(256, 2) void attn_kernel(
    const ushort_t* __restrict__ Qu, const ushort_t* __restrict__ Qv,
    const ushort_t* __restrict__ Kp, const ushort_t* __restrict__ Pp,
    const ushort_t* __restrict__ Vt, ushort_t* __restrict__ ctxb) {
    __shared__ ushort_t sc[32][1032];
    __shared__ float red1[4][32];
    __shared__ float red2[32][8];
    __shared__ float rowinv[32];

    constexpr float SCL = (float)(1.4426950408889634 / 22.627416997969522);

    // XCD swizzle: dispatch i -> XCD i%8 (heuristic). Give each XCD a
    // contiguous run of 8 bh so its K/P/V working set (~3MB) fits its L2.
    int i = blockIdx.x;
    int bh = (i & 7) * 8 + (i >> 8);
    int q0 = ((i >> 3) & 31) << 5;

    int tid = threadIdx.x, wid = tid >> 6, lane = tid & 63;
    int quad = lane >> 4, l16 = lane & 15;

    const ushort_t* Qu_b = Qu + (size_t)bh * S_LEN * DHEAD;
    const ushort_t* Qv_b = Qv + (size_t)bh * S_LEN * DHEAD;
    const ushort_t* K_b  = Kp + (size_t)bh * S_LEN * DHEAD;
    const ushort_t* P_b  = Pp + (size_t)bh * S_LEN * DHEAD;
    const ushort_t* V_b  = Vt + (size_t)bh * DHEAD * S_LEN;

    int kw0 = wid << 8, kw1 = kw0 + 256;
    int d0 = wid << 4;

    bf16x8 au0[2], au1[2];
#pragma unroll
    for (int kc = 0; kc < 2; kc++) {
        au0[kc] = load8(Qu_b + (size_t)(q0 + l16) * 64 + kc * 32 + quad * 8);
        au1[kc] = load8(Qu_b + (size_t)(q0 + 16 + l16) * 64 + kc * 32 + quad * 8);
    }

    // zero-fill k = q+1 inside this wave's range
    if (lane < 32) {
        int kz = q0 + lane + 1;
        if (kz >= kw0 && kz < kw1) sc[lane][kz] = 0;
    }

    // ---- pos scores ----
#pragma unroll
    for (int mt = 0; mt < 2; mt++) {
        int q0m = q0 + mt * 16;
        bf16x8 av1[2], av2[2];
#pragma unroll
        for (int kc = 0; kc < 2; kc++) {
            av1[kc] = load8(Qv_b + (size_t)(q0m + l16) * 64 + kc * 32 + quad * 8);
            int r2 = q0m + 1 + l16; if (r2 > S_LEN - 1) r2 = S_LEN - 1;
            av2[kc] = load8(Qv_b + (size_t)r2 * 64 + kc * 32 + quad * 8);
        }
        int wlo = (S_LEN - 16) - q0m + kw0;
        int d1 = kw1 - 1 - q0m; if (d1 > 0) d1 = 0;
        int whi = (S_LEN - 1) + d1;
        pos_pass(P_b, sc, av1, wlo, whi, q0m - (S_LEN - 1), S_LEN - 1,
                 mt * 16, kw0, kw1, quad, l16);
        int wlo2 = kw0 - q0m - 17; if (wlo2 < 0) wlo2 = 0;
        int whi2 = kw1 - 3 - q0m;
        pos_pass(P_b, sc, av2, wlo2, whi2, q0m + 2, 1 << 30,
                 mt * 16, kw0, kw1, quad, l16);
    }

    // ---- content pass (fully unrolled; compiler hoists K loads) ----
    float pm0[4] = {-1e30f, -1e30f, -1e30f, -1e30f};
    float pm1[4] = {-1e30f, -1e30f, -1e30f, -1e30f};
    const ushort_t* Kw = K_b + (size_t)kw0 * 64;
#pragma unroll
    for (int nt = 0; nt < 16; ++nt) {
        const ushort_t* kp = Kw + (size_t)(nt * 16 + l16) * 64;
        bf16x8 b0 = load8(kp + quad * 8);
        bf16x8 b1 = load8(kp + 32 + quad * 8);
        int kt = kw0 + nt * 16;
        f32x4 a0, a1;
#pragma unroll
        for (int r = 0; r < 4; r++) {
            a0[r] = bf2f(sc[quad * 4 + r][kt + l16]);
            a1[r] = bf2f(sc[16 + quad * 4 + r][kt + l16]);
        }
        a0 = __builtin_amdgcn_mfma_f32_16x16x32_bf16(au0[0], b0, a0, 0, 0, 0);
        a0 = __builtin_amdgcn_mfma_f32_16x16x32_bf16(au0[1], b1, a0, 0, 0, 0);
        a1 = __builtin_amdgcn_mfma_f32_16x16x32_bf16(au1[0], b0, a1, 0, 0, 0);
        a1 = __builtin_amdgcn_mfma_f32_16x16x32_bf16(au1[1], b1, a1, 0, 0, 0);
#pragma unroll
        for (int r = 0; r < 4; r++) {
            sc[quad * 4 + r][kt + l16] = f2bf(a0[r]);
            sc[16 + quad * 4 + r][kt + l16] = f2bf(a1[r]);
            pm0[r] = fmaxf(pm0[r], a0[r]);
            pm1[r] = fmaxf(pm1[r], a1[r]);
        }
    }
#pragma unroll
    for (int off = 1; off < 16; off <<= 1)
#pragma unroll
        for (int r = 0; r < 4; r++) {
            pm0[r] = fmaxf(pm0[r], __shfl_xor(pm0[r], off));
            pm1[r] = fmaxf(pm1[r], __shfl_xor(pm1[r], off));
        }
    if (l16 == 0) {
#pragma unroll
        for (int r = 0; r < 4; r++) {
            red1[wid][quad * 4 + r] = pm0[r];
            red1[wid][16 + quad * 4 + r] = pm1[r];
        }
    }
    __syncthreads();   // B1

    // ---- softmax: thread (row=tid&31, cb=tid>>5) owns cols [cb*128,+128) ----
    int row = tid & 31, cb = tid >> 5;
    float rm = fmaxf(fmaxf(red1[0][row], red1[1][row]), fmaxf(red1[2][row], red1[3][row]));
    float ssum = 0.f;
    ushort_t* sp = &sc[row][cb * 128];
#pragma unroll
    for (int j = 0; j < 16; j++) {
        union { uint4 u; ushort_t s[8]; } in, out;
        in.u = *reinterpret_cast<uint4*>(sp + j * 8);
#pragma unroll
        for (int e = 0; e < 8; e++) {
            float ev = exp2f((bf2f(in.s[e]) - rm) * SCL);
            out.s[e] = f2bf(ev);
            ssum += ev;
        }
        *reinterpret_cast<uint4*>(sp + j * 8) = out.u;
    }
    red2[row][cb] = ssum;
    __syncthreads();   // B2
    if (tid < 32) {
        float s = 0.f;
#pragma unroll
        for (int c = 0; c < 8; c++) s += red2[tid][c];
        rowinv[tid] = 1.0f / s;
    }

    // ---- PV (fully unrolled; compiler hoists V loads) ----
    const ushort_t* Vw = V_b + (size_t)(d0 + l16) * 1024;
    f32x4 ac0 = (f32x4){0.f, 0.f, 0.f, 0.f};
    f32x4 ac1 = (f32x4){0.f, 0.f, 0.f, 0.f};
#pragma unroll
    for (int kc = 0; kc < 32; ++kc) {
        bf16x8 b = load8(Vw + kc * 32 + quad * 8);
        bf16x8 a0 = load8(&sc[l16][kc * 32 + quad * 8]);
        bf16x8 a1 = load8(&sc[16 + l16][kc * 32 + quad * 8]);
        ac0 = __builtin_amdgcn_mfma_f32_16x16x32_bf16(a0, b, ac0, 0, 0, 0);
        ac1 = __builtin_amdgcn_mfma_f32_16x16x32_bf16(a1, b, ac1, 0, 0, 0);
    }
    __syncthreads();   // B3 (rowinv visibility)
    int b_ = bh >> 3, h_ = bh & 7;
#pragma unroll
    for (int r = 0; r < 4; r++) {
        int m = quad * 4 + r;
        ctxb[((size_t)b_ * 1024 + (q0 + m)) * 512 + h_ * 64 + d0 + l16] =
            f2bf(ac0[r] * rowinv[m]);
        ctxb[((size_t)b_ * 1024 + (q0 + 16 + m)) * 512 + h_ * 64 + d0 + l16] =
            f2bf(ac1[r] * rowinv[16 + m]);
    }
}

extern "C" void kernel_launch(void* const* d_in, const int* in_sizes, int n_in,
                              void* d_out, int out_size, void* d_ws, size_t ws_size,
                              hipStream_t stream) {
    const float* q  = (const float*)d_in[0];
    const float* k  = (const float*)d_in[1];
    const float* v  = (const float*)d_in[2];
    const float* pe = (const float*)d_in[3];
    const float* Wq = (const float*)d_in[4];
    const float* bq = (const float*)d_in[5];
    const float* Wk = (const float*)d_in[6];
    const float* bk = (const float*)d_in[7];
    const float* Wv = (const float*)d_in[8];
    const float* bv = (const float*)d_in[9];
    const float* Wp = (const float*)d_in[10];
    const float* ub = (const float*)d_in[11];
    const float* vbias = (const float*)d_in[12];
    const float* Wo = (const float*)d_in[13];
    const float* bo = (const float*)d_in[14];
    float* out = (float*)d_out;
    ushort_t* ws = (ushort_t*)d_ws;

    ushort_t* wT  = ws;                       // 5 x 262144 = 1,310,720
    ushort_t* Qu  = ws + 1310720;
    ushort_t* Qv  = Qu + 4194304;
    ushort_t* Kp  = Qv + 4194304;
    ushort_t* Pp  = Kp + 4194304;
    ushort_t* Vt  = Pp + 4194304;
    ushort_t* actb = Vt + 4194304;            // big path: 4 x 4,194,304
    ushort_t* ctx_big = actb;                 // alias act[0]: dead after proj

    const size_t need_big = (size_t)(1310720 + 9 * 4194304) * 2;  // ~78.1 MB
    bool big = ws_size >= need_big;

    prep_w<<<dim3(8, 8, 5), 256, 0, stream>>>(Wq, Wk, Wv, Wp, Wo, wT);
    if (big) {
        prep_act<<<dim3(4096, 4), 256, 0, stream>>>(q, k, v, pe, actb);
        proj_gemm<0><<<dim3(4, 64, 4), 256, 0, stream>>>(q, k, v, pe, actb, wT,
            bq, bk, bv, ub, vbias, Qu, Qv, Kp, Pp, Vt);
        attn_kernel<<<2048, 256, 0, stream>>>(Qu, Qv, Kp, Pp, Vt, ctx_big);
        out_gemm<<<dim3(8, 64), 256, 0, stream>>>(ctx_big, wT + 4 * 262144, bo, out);
    } else {
        ushort_t* ctx = actb;
        proj_gemm<1><<<dim3(4, 64, 4), 256, 0, stream>>>(q, k, v, pe, nullptr, wT,
            bq, bk, bv, ub, vbias, Qu, Qv, Kp, Pp, Vt);
        attn_kernel<<<2048, 256, 0, stream>>>(Qu, Qv, Kp, Pp, Vt, ctx);
        out_gemm<<<dim3(8, 64), 256, 0, stream>>>(ctx, wT + 4 * 262144, bo, out);
    }
}